// Round 2
// baseline (996.250 us; speedup 1.0000x reference)
//
#include <hip/hip_runtime.h>
#include <hip/hip_bf16.h>

// Glm4MoE: B=1,S=2048,D=1024, E=64,K=8,F=768, SF=768, C=512, ROUTED_SCALE=1
//
// R2: pre-convert+transpose all weights f32->bf16 [n][k] in one streaming
// pass, then run all GEMMs m97-style: global_load_lds width=16 for A and B,
// linear [rows][32] LDS (conflict-free b128 fragment reads), no VALU staging
// work in the K-loop. Falls back to the R1 path if ws_size < ~357 MB.

typedef unsigned int uint;
typedef unsigned short ushort;
typedef __bf16 v8bf __attribute__((ext_vector_type(8)));
typedef float v4f __attribute__((ext_vector_type(4)));

#define MFMA_BF16 __builtin_amdgcn_mfma_f32_16x16x32_bf16

#define NTOK 2048
#define DMODEL 1024
#define NEXP 64
#define TOPK 8
#define FFN 768
#define CAP 512

#define LDSW 40  // fallback-path LDS stride

__device__ inline ushort f2bf(float f) {
    uint u = __float_as_uint(f);
    u = (u + 0x7FFFu + ((u >> 16) & 1u)) >> 16;
    return (ushort)u;
}
__device__ inline uint pkbf(float lo, float hi) {
    __hip_bfloat162 h = __float22bfloat162_rn(float2{lo, hi});
    uint u;
    __builtin_memcpy(&u, &h, 4);
    return u;
}

// async global->LDS, 16B per lane; LDS dest = wave-uniform base + lane*16
__device__ inline void gll16(const void* g, void* l) {
    __builtin_amdgcn_global_load_lds(
        (__attribute__((address_space(1))) void*)(g),
        (__attribute__((address_space(3))) void*)(l), 16, 0, 0);
}

// ------------------------------------------------------------- x -> bf16 ----
__global__ __launch_bounds__(256) void x2bf_kernel(
    const float* __restrict__ X, ushort* __restrict__ Xb)
{
    int i = (blockIdx.x * 256 + threadIdx.x) * 4;
    float4 v = *(const float4*)(X + i);
    uint2 o;
    o.x = pkbf(v.x, v.y);
    o.y = pkbf(v.z, v.w);
    *(uint2*)(Xb + i) = o;
}

// ---------------------------------------------------------------- router ----
__global__ __launch_bounds__(64) void router_kernel(
    const float* __restrict__ X, const float* __restrict__ RW,
    int* __restrict__ counts, int* __restrict__ tok_map,
    float* __restrict__ wt_map)
{
    const int t = blockIdx.x;
    const int lane = threadIdx.x;  // == expert id
    const float* xr = X + (size_t)t * DMODEL;
    const float* wr = RW + (size_t)lane * DMODEL;
    float sum = 0.f;
    for (int d = 0; d < DMODEL; d += 4) {
        float4 a = *(const float4*)(wr + d);
        float4 b = *(const float4*)(xr + d);
        sum += a.x * b.x + a.y * b.y + a.z * b.z + a.w * b.w;
    }
    float mx = sum;
    for (int off = 32; off; off >>= 1) mx = fmaxf(mx, __shfl_xor(mx, off));
    float p = __expf(sum - mx);

    float v = p;
    float my_p = 0.f;
    int my_e = 0;
    for (int it = 0; it < TOPK; ++it) {
        float m = v;
        int mi = lane;
        for (int off = 32; off; off >>= 1) {
            float om = __shfl_xor(m, off);
            int oi = __shfl_xor(mi, off);
            if (om > m || (om == m && oi < mi)) { m = om; mi = oi; }
        }
        if (lane == it) { my_p = m; my_e = mi; }
        if (lane == mi) v = -1.f;
    }
    float s = (lane < TOPK) ? my_p : 0.f;
    for (int off = 32; off; off >>= 1) s += __shfl_xor(s, off);
    if (lane < TOPK) {
        float w = my_p / s;
        int slot = atomicAdd(&counts[my_e], 1);
        if (slot < CAP) {
            tok_map[my_e * CAP + slot] = t;
            wt_map[my_e * CAP + slot] = w;
        }
    }
}

// ----------------------------------------------- convert+transpose weights --
// in [R][Cn] f32 -> out [Cn][R] bf16, 64x64 tiles via LDS.
// z: 0..63 Wg, 64..127 Wu, 128..191 Wd, 192 wsgu, 193 wsd
__global__ __launch_bounds__(256) void cvt_t(
    const float* __restrict__ Wg, const float* __restrict__ Wu,
    const float* __restrict__ Wd, const float* __restrict__ Wsgu,
    const float* __restrict__ Wsd,
    ushort* __restrict__ Wgt, ushort* __restrict__ Wut,
    ushort* __restrict__ Wdt, ushort* __restrict__ Wsgut,
    ushort* __restrict__ Wsdt)
{
    const int z = blockIdx.z;
    const float* in;
    ushort* out;
    int R, Cn;
    if (z < 64)       { in = Wg + (size_t)z * 786432;        out = Wgt + (size_t)z * 786432;        R = 1024; Cn = 768;  }
    else if (z < 128) { in = Wu + (size_t)(z - 64) * 786432; out = Wut + (size_t)(z - 64) * 786432; R = 1024; Cn = 768;  }
    else if (z < 192) { in = Wd + (size_t)(z - 128) * 786432; out = Wdt + (size_t)(z - 128) * 786432; R = 768; Cn = 1024; }
    else if (z == 192){ in = Wsgu; out = Wsgut; R = 1024; Cn = 1536; }
    else              { in = Wsd;  out = Wsdt;  R = 768;  Cn = 1024; }
    const int r0 = blockIdx.y * 64, c0 = blockIdx.x * 64;
    if (r0 >= R || c0 >= Cn) return;

    __shared__ float t[64][65];
    const int l = threadIdx.x & 31, g = threadIdx.x >> 5;  // 8 groups x 32 lanes
#pragma unroll
    for (int i = 0; i < 8; ++i) {
        int r = g * 8 + i;
        float2 v = *(const float2*)(in + (size_t)(r0 + r) * Cn + c0 + l * 2);
        t[r][l * 2] = v.x;
        t[r][l * 2 + 1] = v.y;
    }
    __syncthreads();
#pragma unroll
    for (int i = 0; i < 8; ++i) {
        int c = g * 8 + i;
        uint p = pkbf(t[l * 2][c], t[l * 2 + 1][c]);
        *(uint*)(out + (size_t)(c0 + c) * R + r0 + l * 2) = p;
    }
}

// ------------------------------------------------------- gemm gate/up (v2) --
// 128 rows x 64 F-cols, two B panels (gate/up), BK=32, 4 waves 2x2.
// All staging via global_load_lds; weights bf16 [f][d].
__global__ __launch_bounds__(256) void gemm_gu_v2(
    const ushort* __restrict__ Xb,
    const ushort* __restrict__ Wgt, const ushort* __restrict__ Wut,
    const ushort* __restrict__ Wsgut,  // [1536][1024]: gate rows 0..767, up 768..1535
    ushort* __restrict__ H, ushort* __restrict__ Hs,
    const int* __restrict__ tok_map, const int* __restrict__ counts)
{
    const int e = blockIdx.z;
    const bool sh = (e == NEXP);
    const int rows = sh ? NTOK : min(counts[e], CAP);
    const int mtile = blockIdx.y, ntile = blockIdx.x;
    if (mtile * 128 >= rows) return;

    const ushort* Bgp = sh ? (Wsgut + (size_t)(ntile * 64) * DMODEL)
                           : (Wgt + ((size_t)e * FFN + ntile * 64) * DMODEL);
    const ushort* Bup = sh ? (Wsgut + (size_t)(FFN + ntile * 64) * DMODEL)
                           : (Wut + ((size_t)e * FFN + ntile * 64) * DMODEL);
    ushort* Hbase = sh ? Hs : (H + (size_t)e * CAP * FFN);

    __shared__ ushort As[128 * 32];
    __shared__ ushort Bgs[64 * 32];
    __shared__ ushort Bus[64 * 32];

    const int tid = threadIdx.x;
    const int lane = tid & 63, w = tid >> 6;

    // A: wave w stages rows [w*32, w*32+32); 2 calls of 16 rows each
    const int r0g = mtile * 128 + w * 32 + (lane >> 2);
    const int s0 = min(r0g, rows - 1);
    const int s1 = min(r0g + 16, rows - 1);
    const int t0 = sh ? s0 : tok_map[e * CAP + s0];
    const int t1 = sh ? s1 : tok_map[e * CAP + s1];
    const ushort* aSrc0 = Xb + (size_t)t0 * DMODEL + (lane & 3) * 8;
    const ushort* aSrc1 = Xb + (size_t)t1 * DMODEL + (lane & 3) * 8;
    // B: wave w stages f-rows [w*16, w*16+16); 1 call per panel
    const ushort* gSrc = Bgp + (size_t)(w * 16 + (lane >> 2)) * DMODEL + (lane & 3) * 8;
    const ushort* uSrc = Bup + (size_t)(w * 16 + (lane >> 2)) * DMODEL + (lane & 3) * 8;

    ushort* aDst0 = &As[w * 1024];
    ushort* aDst1 = &As[w * 1024 + 512];
    ushort* gDst = &Bgs[w * 512];
    ushort* uDst = &Bus[w * 512];

    const int wm = (w & 1) * 64, wn = (w >> 1) * 32;
    const int lr = lane & 15, lq = lane >> 4;

    v4f accg[4][2] = {};
    v4f accu[4][2] = {};

    for (int k0 = 0; k0 < DMODEL; k0 += 32) {
        gll16(aSrc0 + k0, aDst0);
        gll16(aSrc1 + k0, aDst1);
        gll16(gSrc + k0, gDst);
        gll16(uSrc + k0, uDst);
        __syncthreads();  // drains vmcnt(0): LDS tiles ready

        v8bf a[4], bg[2], bu[2];
#pragma unroll
        for (int mi = 0; mi < 4; ++mi)
            a[mi] = *(const v8bf*)&As[(wm + mi * 16 + lr) * 32 + lq * 8];
#pragma unroll
        for (int ni = 0; ni < 2; ++ni) {
            bg[ni] = *(const v8bf*)&Bgs[(wn + ni * 16 + lr) * 32 + lq * 8];
            bu[ni] = *(const v8bf*)&Bus[(wn + ni * 16 + lr) * 32 + lq * 8];
        }
#pragma unroll
        for (int mi = 0; mi < 4; ++mi)
#pragma unroll
            for (int ni = 0; ni < 2; ++ni) {
                accg[mi][ni] = MFMA_BF16(a[mi], bg[ni], accg[mi][ni], 0, 0, 0);
                accu[mi][ni] = MFMA_BF16(a[mi], bu[ni], accu[mi][ni], 0, 0, 0);
            }
        __syncthreads();  // all reads done before next iter's gll overwrites
    }

#pragma unroll
    for (int mi = 0; mi < 4; ++mi)
#pragma unroll
        for (int ni = 0; ni < 2; ++ni)
#pragma unroll
            for (int r = 0; r < 4; ++r) {
                float g = accg[mi][ni][r];
                float u = accu[mi][ni][r];
                float h = (g / (1.f + __expf(-g))) * u;  // silu(g)*u
                int row = mtile * 128 + wm + mi * 16 + lq * 4 + r;
                int col = ntile * 64 + wn + ni * 16 + lr;
                Hbase[(size_t)row * FFN + col] = f2bf(h);
            }
}

// --------------------------------------------------------- down shared (v2) -
// out[t][:] = Hs @ Wsdt^T ; tile 128x128, 4 waves 2x2 (wave 64x64)
__global__ __launch_bounds__(256) void down_shared_v2(
    const ushort* __restrict__ Hs, const ushort* __restrict__ Wsdt,  // [1024][768]
    float* __restrict__ Out)
{
    const int mtile = blockIdx.y, ntile = blockIdx.x;

    __shared__ ushort As[128 * 32];
    __shared__ ushort Bs[128 * 32];

    const int tid = threadIdx.x;
    const int lane = tid & 63, w = tid >> 6;

    const ushort* aSrc0 = Hs + (size_t)(mtile * 128 + w * 32 + (lane >> 2)) * FFN + (lane & 3) * 8;
    const ushort* aSrc1 = aSrc0 + (size_t)16 * FFN;
    const ushort* bSrc0 = Wsdt + (size_t)(ntile * 128 + w * 32 + (lane >> 2)) * FFN + (lane & 3) * 8;
    const ushort* bSrc1 = bSrc0 + (size_t)16 * FFN;

    ushort* aDst0 = &As[w * 1024];
    ushort* aDst1 = &As[w * 1024 + 512];
    ushort* bDst0 = &Bs[w * 1024];
    ushort* bDst1 = &Bs[w * 1024 + 512];

    const int wm = (w & 1) * 64, wn = (w >> 1) * 64;
    const int lr = lane & 15, lq = lane >> 4;

    v4f acc[4][4] = {};

    for (int k0 = 0; k0 < FFN; k0 += 32) {
        gll16(aSrc0 + k0, aDst0);
        gll16(aSrc1 + k0, aDst1);
        gll16(bSrc0 + k0, bDst0);
        gll16(bSrc1 + k0, bDst1);
        __syncthreads();

        v8bf a[4], b[4];
#pragma unroll
        for (int mi = 0; mi < 4; ++mi)
            a[mi] = *(const v8bf*)&As[(wm + mi * 16 + lr) * 32 + lq * 8];
#pragma unroll
        for (int ni = 0; ni < 4; ++ni)
            b[ni] = *(const v8bf*)&Bs[(wn + ni * 16 + lr) * 32 + lq * 8];
#pragma unroll
        for (int mi = 0; mi < 4; ++mi)
#pragma unroll
            for (int ni = 0; ni < 4; ++ni)
                acc[mi][ni] = MFMA_BF16(a[mi], b[ni], acc[mi][ni], 0, 0, 0);
        __syncthreads();
    }

#pragma unroll
    for (int mi = 0; mi < 4; ++mi)
#pragma unroll
        for (int ni = 0; ni < 4; ++ni)
#pragma unroll
            for (int r = 0; r < 4; ++r) {
                int row = mtile * 128 + wm + mi * 16 + lq * 4 + r;
                int col = ntile * 128 + wn + ni * 16 + lr;
                Out[(size_t)row * DMODEL + col] = acc[mi][ni][r];
            }
}

// --------------------------------------------------------- down routed (v2) -
// out[tok][:] += w * (H[e] @ Wdt[e]^T)  via f32 atomicAdd; tile 128x128
__global__ __launch_bounds__(256) void down_routed_v2(
    const ushort* __restrict__ H, const ushort* __restrict__ Wdt,  // [64][1024][768]
    float* __restrict__ Out,
    const int* __restrict__ tok_map, const float* __restrict__ wt_map,
    const int* __restrict__ counts)
{
    const int e = blockIdx.z;
    const int rows = min(counts[e], CAP);
    const int mtile = blockIdx.y, ntile = blockIdx.x;
    if (mtile * 128 >= rows) return;

    const ushort* A = H + (size_t)e * CAP * FFN;
    const ushort* B = Wdt + ((size_t)e * DMODEL + ntile * 128) * FFN;

    __shared__ ushort As[128 * 32];
    __shared__ ushort Bs[128 * 32];

    const int tid = threadIdx.x;
    const int lane = tid & 63, w = tid >> 6;

    const ushort* aSrc0 = A + (size_t)(mtile * 128 + w * 32 + (lane >> 2)) * FFN + (lane & 3) * 8;
    const ushort* aSrc1 = aSrc0 + (size_t)16 * FFN;
    const ushort* bSrc0 = B + (size_t)(w * 32 + (lane >> 2)) * FFN + (lane & 3) * 8;
    const ushort* bSrc1 = bSrc0 + (size_t)16 * FFN;

    ushort* aDst0 = &As[w * 1024];
    ushort* aDst1 = &As[w * 1024 + 512];
    ushort* bDst0 = &Bs[w * 1024];
    ushort* bDst1 = &Bs[w * 1024 + 512];

    const int wm = (w & 1) * 64, wn = (w >> 1) * 64;
    const int lr = lane & 15, lq = lane >> 4;

    v4f acc[4][4] = {};

    for (int k0 = 0; k0 < FFN; k0 += 32) {
        gll16(aSrc0 + k0, aDst0);
        gll16(aSrc1 + k0, aDst1);
        gll16(bSrc0 + k0, bDst0);
        gll16(bSrc1 + k0, bDst1);
        __syncthreads();

        v8bf a[4], b[4];
#pragma unroll
        for (int mi = 0; mi < 4; ++mi)
            a[mi] = *(const v8bf*)&As[(wm + mi * 16 + lr) * 32 + lq * 8];
#pragma unroll
        for (int ni = 0; ni < 4; ++ni)
            b[ni] = *(const v8bf*)&Bs[(wn + ni * 16 + lr) * 32 + lq * 8];
#pragma unroll
        for (int mi = 0; mi < 4; ++mi)
#pragma unroll
            for (int ni = 0; ni < 4; ++ni)
                acc[mi][ni] = MFMA_BF16(a[mi], b[ni], acc[mi][ni], 0, 0, 0);
        __syncthreads();
    }

#pragma unroll
    for (int mi = 0; mi < 4; ++mi)
#pragma unroll
        for (int ni = 0; ni < 4; ++ni)
#pragma unroll
            for (int r = 0; r < 4; ++r) {
                int gslot = mtile * 128 + wm + mi * 16 + lq * 4 + r;
                if (gslot < rows) {
                    int t = tok_map[e * CAP + gslot];
                    float wv = wt_map[e * CAP + gslot];
                    int col = ntile * 128 + wn + ni * 16 + lr;
                    atomicAdd(&Out[(size_t)t * DMODEL + col], wv * acc[mi][ni][r]);
                }
            }
}

// ======================= FALLBACK PATH (R1, f32 weights) ====================
__global__ __launch_bounds__(256) void gemm_gu_fb(
    const ushort* __restrict__ Xb,
    const float* __restrict__ Wg_all, const float* __restrict__ Wu_all,
    const float* __restrict__ Wshared,
    ushort* __restrict__ H, ushort* __restrict__ Hs,
    const int* __restrict__ tok_map, const int* __restrict__ counts)
{
    const int e = blockIdx.z;
    const bool sh = (e == NEXP);
    const int rows = sh ? NTOK : min(counts[e], CAP);
    const int mtile = blockIdx.y, ntile = blockIdx.x;
    if (mtile * 128 >= rows) return;

    const float* Wg;
    const float* Wu;
    int ldw;
    ushort* Hbase;
    if (sh) {
        Wg = Wshared + ntile * 64;
        Wu = Wshared + FFN + ntile * 64;
        ldw = 2 * FFN;
        Hbase = Hs;
    } else {
        Wg = Wg_all + (size_t)e * DMODEL * FFN + ntile * 64;
        Wu = Wu_all + (size_t)e * DMODEL * FFN + ntile * 64;
        ldw = FFN;
        Hbase = H + (size_t)e * CAP * FFN;
    }

    __shared__ ushort As[128 * LDSW];
    __shared__ ushort Bg[64 * LDSW];
    __shared__ ushort Bu[64 * LDSW];

    const int tid = threadIdx.x;
    const int ar = tid >> 1, ah = (tid & 1) * 16;
    const int gslot = mtile * 128 + ar;
    const ushort* aptr = nullptr;
    if (gslot < rows) {
        int row = sh ? gslot : tok_map[e * CAP + gslot];
        aptr = Xb + (size_t)row * DMODEL + ah;
    }
    const int bn2 = (tid & 31) * 2, bkg = (tid >> 5) * 4;
    const float* gptr = Wg + (size_t)bkg * ldw + bn2;
    const float* uptr = Wu + (size_t)bkg * ldw + bn2;

    const int lane = tid & 63, wv = tid >> 6;
    const int wm = (wv & 1) * 64, wn = (wv >> 1) * 32;
    const int lr = lane & 15, lq = lane >> 4;

    v4f accg[4][2] = {};
    v4f accu[4][2] = {};

    for (int k0 = 0; k0 < DMODEL; k0 += 32) {
        uint4 a0 = make_uint4(0, 0, 0, 0), a1 = make_uint4(0, 0, 0, 0);
        if (aptr) {
            a0 = *(const uint4*)(aptr + k0);
            a1 = *(const uint4*)(aptr + k0 + 8);
        }
        const float* gp = gptr + (size_t)k0 * ldw;
        const float* up = uptr + (size_t)k0 * ldw;
        float2 g0 = *(const float2*)(gp);
        float2 g1 = *(const float2*)(gp + ldw);
        float2 g2 = *(const float2*)(gp + 2 * ldw);
        float2 g3 = *(const float2*)(gp + 3 * ldw);
        float2 u0 = *(const float2*)(up);
        float2 u1 = *(const float2*)(up + ldw);
        float2 u2 = *(const float2*)(up + 2 * ldw);
        float2 u3 = *(const float2*)(up + 3 * ldw);
        __syncthreads();
        *(uint4*)&As[ar * LDSW + ah] = a0;
        *(uint4*)&As[ar * LDSW + ah + 8] = a1;
        {
            uint2 lo, hi;
            lo.x = pkbf(g0.x, g1.x); lo.y = pkbf(g2.x, g3.x);
            hi.x = pkbf(g0.y, g1.y); hi.y = pkbf(g2.y, g3.y);
            *(uint2*)&Bg[bn2 * LDSW + bkg] = lo;
            *(uint2*)&Bg[(bn2 + 1) * LDSW + bkg] = hi;
        }
        {
            uint2 lo, hi;
            lo.x = pkbf(u0.x, u1.x); lo.y = pkbf(u2.x, u3.x);
            hi.x = pkbf(u0.y, u1.y); hi.y = pkbf(u2.y, u3.y);
            *(uint2*)&Bu[bn2 * LDSW + bkg] = lo;
            *(uint2*)&Bu[(bn2 + 1) * LDSW + bkg] = hi;
        }
        __syncthreads();

        v8bf a[4], bg[2], bu[2];
#pragma unroll
        for (int mi = 0; mi < 4; ++mi)
            a[mi] = *(const v8bf*)&As[(wm + mi * 16 + lr) * LDSW + lq * 8];
#pragma unroll
        for (int ni = 0; ni < 2; ++ni) {
            bg[ni] = *(const v8bf*)&Bg[(wn + ni * 16 + lr) * LDSW + lq * 8];
            bu[ni] = *(const v8bf*)&Bu[(wn + ni * 16 + lr) * LDSW + lq * 8];
        }
#pragma unroll
        for (int mi = 0; mi < 4; ++mi)
#pragma unroll
            for (int ni = 0; ni < 2; ++ni) {
                accg[mi][ni] = MFMA_BF16(a[mi], bg[ni], accg[mi][ni], 0, 0, 0);
                accu[mi][ni] = MFMA_BF16(a[mi], bu[ni], accu[mi][ni], 0, 0, 0);
            }
    }

#pragma unroll
    for (int mi = 0; mi < 4; ++mi)
#pragma unroll
        for (int ni = 0; ni < 2; ++ni)
#pragma unroll
            for (int r = 0; r < 4; ++r) {
                float g = accg[mi][ni][r];
                float u = accu[mi][ni][r];
                float h = (g / (1.f + __expf(-g))) * u;
                int row = mtile * 128 + wm + mi * 16 + lq * 4 + r;
                int col = ntile * 64 + wn + ni * 16 + lr;
                Hbase[(size_t)row * FFN + col] = f2bf(h);
            }
}

__global__ __launch_bounds__(256) void down_shared_fb(
    const ushort* __restrict__ Hs, const float* __restrict__ Wsd,
    float* __restrict__ Out)
{
    const int mtile = blockIdx.y, ntile = blockIdx.x;

    __shared__ ushort As[128 * LDSW];
    __shared__ ushort Bt[64 * LDSW];

    const int tid = threadIdx.x;
    const int ar = tid >> 1, ah = (tid & 1) * 16;
    const ushort* aptr = Hs + (size_t)(mtile * 128 + ar) * FFN + ah;
    const int bn2 = (tid & 31) * 2, bkg = (tid >> 5) * 4;
    const float* wptr = Wsd + (size_t)bkg * DMODEL + ntile * 64 + bn2;

    const int lane = tid & 63, wv = tid >> 6;
    const int wm = (wv & 1) * 64, wn = (wv >> 1) * 32;
    const int lr = lane & 15, lq = lane >> 4;

    v4f accv[4][2] = {};

    for (int k0 = 0; k0 < FFN; k0 += 32) {
        uint4 a0 = *(const uint4*)(aptr + k0);
        uint4 a1 = *(const uint4*)(aptr + k0 + 8);
        const float* wp = wptr + (size_t)k0 * DMODEL;
        float2 g0 = *(const float2*)(wp);
        float2 g1 = *(const float2*)(wp + DMODEL);
        float2 g2 = *(const float2*)(wp + 2 * DMODEL);
        float2 g3 = *(const float2*)(wp + 3 * DMODEL);
        __syncthreads();
        *(uint4*)&As[ar * LDSW + ah] = a0;
        *(uint4*)&As[ar * LDSW + ah + 8] = a1;
        {
            uint2 lo, hi;
            lo.x = pkbf(g0.x, g1.x); lo.y = pkbf(g2.x, g3.x);
            hi.x = pkbf(g0.y, g1.y); hi.y = pkbf(g2.y, g3.y);
            *(uint2*)&Bt[bn2 * LDSW + bkg] = lo;
            *(uint2*)&Bt[(bn2 + 1) * LDSW + bkg] = hi;
        }
        __syncthreads();

        v8bf a[4], b[2];
#pragma unroll
        for (int mi = 0; mi < 4; ++mi)
            a[mi] = *(const v8bf*)&As[(wm + mi * 16 + lr) * LDSW + lq * 8];
#pragma unroll
        for (int ni = 0; ni < 2; ++ni)
            b[ni] = *(const v8bf*)&Bt[(wn + ni * 16 + lr) * LDSW + lq * 8];
#pragma unroll
        for (int mi = 0; mi < 4; ++mi)
#pragma unroll
            for (int ni = 0; ni < 2; ++ni)
                accv[mi][ni] = MFMA_BF16(a[mi], b[ni], accv[mi][ni], 0, 0, 0);
    }

#pragma unroll
    for (int mi = 0; mi < 4; ++mi)
#pragma unroll
        for (int ni = 0; ni < 2; ++ni)
#pragma unroll
            for (int r = 0; r < 4; ++r) {
                int row = mtile * 128 + wm + mi * 16 + lq * 4 + r;
                int col = ntile * 64 + wn + ni * 16 + lr;
                Out[(size_t)row * DMODEL + col] = accv[mi][ni][r];
            }
}

__global__ __launch_bounds__(256) void down_routed_fb(
    const ushort* __restrict__ H, const float* __restrict__ Wd_all,
    float* __restrict__ Out,
    const int* __restrict__ tok_map, const float* __restrict__ wt_map,
    const int* __restrict__ counts)
{
    const int e = blockIdx.z;
    const int rows = min(counts[e], CAP);
    const int mtile = blockIdx.y, ntile = blockIdx.x;
    if (mtile * 128 >= rows) return;

    const ushort* A = H + (size_t)e * CAP * FFN;
    const float* W = Wd_all + (size_t)e * FFN * DMODEL + ntile * 64;

    __shared__ ushort As[128 * LDSW];
    __shared__ ushort Bt[64 * LDSW];

    const int tid = threadIdx.x;
    const int ar = tid >> 1, ah = (tid & 1) * 16;
    const ushort* aptr = A + (size_t)(mtile * 128 + ar) * FFN + ah;
    const int bn2 = (tid & 31) * 2, bkg = (tid >> 5) * 4;
    const float* wptr = W + (size_t)bkg * DMODEL + bn2;

    const int lane = tid & 63, wv = tid >> 6;
    const int wm = (wv & 1) * 64, wn = (wv >> 1) * 32;
    const int lr = lane & 15, lq = lane >> 4;

    v4f accv[4][2] = {};

    for (int k0 = 0; k0 < FFN; k0 += 32) {
        uint4 a0 = *(const uint4*)(aptr + k0);
        uint4 a1 = *(const uint4*)(aptr + k0 + 8);
        const float* wp = wptr + (size_t)k0 * DMODEL;
        float2 g0 = *(const float2*)(wp);
        float2 g1 = *(const float2*)(wp + DMODEL);
        float2 g2 = *(const float2*)(wp + 2 * DMODEL);
        float2 g3 = *(const float2*)(wp + 3 * DMODEL);
        __syncthreads();
        *(uint4*)&As[ar * LDSW + ah] = a0;
        *(uint4*)&As[ar * LDSW + ah + 8] = a1;
        {
            uint2 lo, hi;
            lo.x = pkbf(g0.x, g1.x); lo.y = pkbf(g2.x, g3.x);
            hi.x = pkbf(g0.y, g1.y); hi.y = pkbf(g2.y, g3.y);
            *(uint2*)&Bt[bn2 * LDSW + bkg] = lo;
            *(uint2*)&Bt[(bn2 + 1) * LDSW + bkg] = hi;
        }
        __syncthreads();

        v8bf a[4], b[2];
#pragma unroll
        for (int mi = 0; mi < 4; ++mi)
            a[mi] = *(const v8bf*)&As[(wm + mi * 16 + lr) * LDSW + lq * 8];
#pragma unroll
        for (int ni = 0; ni < 2; ++ni)
            b[ni] = *(const v8bf*)&Bt[(wn + ni * 16 + lr) * LDSW + lq * 8];
#pragma unroll
        for (int mi = 0; mi < 4; ++mi)
#pragma unroll
            for (int ni = 0; ni < 2; ++ni)
                accv[mi][ni] = MFMA_BF16(a[mi], b[ni], accv[mi][ni], 0, 0, 0);
    }

#pragma unroll
    for (int mi = 0; mi < 4; ++mi)
#pragma unroll
        for (int ni = 0; ni < 2; ++ni)
#pragma unroll
            for (int r = 0; r < 4; ++r) {
                int lrow = wm + mi * 16 + lq * 4 + r;
                int gslot = mtile * 128 + lrow;
                int col = ntile * 64 + wn + ni * 16 + lr;
                if (gslot < rows) {
                    int t = tok_map[e * CAP + gslot];
                    float w = wt_map[e * CAP + gslot];
                    atomicAdd(&Out[(size_t)t * DMODEL + col], w * accv[mi][ni][r]);
                }
            }
}

// ------------------------------------------------------------------ launch --
extern "C" void kernel_launch(void* const* d_in, const int* in_sizes, int n_in,
                              void* d_out, int out_size, void* d_ws, size_t ws_size,
                              hipStream_t stream)
{
    const float* x    = (const float*)d_in[0];  // (1,2048,1024)
    const float* rw   = (const float*)d_in[1];  // (64,1024)
    const float* wg   = (const float*)d_in[2];  // (64,1024,768)
    const float* wu   = (const float*)d_in[3];  // (64,1024,768)
    const float* wd   = (const float*)d_in[4];  // (64,768,1024)
    const float* wsgu = (const float*)d_in[5];  // (1024,1536)
    const float* wsd  = (const float*)d_in[6];  // (768,1024)
    float* out = (float*)d_out;

    char* ws = (char*)d_ws;
    int*    counts = (int*)(ws + 0);
    int*    tok    = (int*)(ws + 4096);
    float*  wt     = (float*)(ws + 139264);
    ushort* Xb     = (ushort*)(ws + ((size_t)1 << 20));

    hipMemsetAsync(counts, 0, NEXP * sizeof(int), stream);
    x2bf_kernel<<<NTOK * DMODEL / 1024, 256, 0, stream>>>(x, Xb);
    router_kernel<<<NTOK, 64, 0, stream>>>(x, rw, counts, tok, wt);

    const size_t NEED = (size_t)357 << 20;
    if (ws_size >= NEED) {
        // new path: bf16 transposed weights + global_load_lds GEMMs
        ushort* Hs    = (ushort*)(ws + ((size_t)6 << 20));    // [2048][768]
        ushort* H     = (ushort*)(ws + ((size_t)16 << 20));   // [64][512][768]
        ushort* Wgt   = (ushort*)(ws + ((size_t)64 << 20));   // [64][768][1024]
        ushort* Wut   = (ushort*)(ws + ((size_t)160 << 20));  // [64][768][1024]
        ushort* Wdt   = (ushort*)(ws + ((size_t)256 << 20));  // [64][1024][768]
        ushort* Wsgut = (ushort*)(ws + ((size_t)352 << 20));  // [1536][1024]
        ushort* Wsdt  = (ushort*)(ws + ((size_t)355 << 20));  // [1024][768]

        cvt_t<<<dim3(24, 16, 194), 256, 0, stream>>>(
            wg, wu, wd, wsgu, wsd, Wgt, Wut, Wdt, Wsgut, Wsdt);

        gemm_gu_v2<<<dim3(12, 16, NEXP + 1), 256, 0, stream>>>(
            Xb, Wgt, Wut, Wsgut, H, Hs, tok, counts);

        down_shared_v2<<<dim3(8, 16), 256, 0, stream>>>(Hs, Wsdt, out);

        down_routed_v2<<<dim3(8, 4, NEXP), 256, 0, stream>>>(
            H, Wdt, out, tok, wt, counts);
    } else {
        // fallback: R1 path (f32 weights, in-kernel cvt+transpose staging)
        ushort* H  = (ushort*)(ws + ((size_t)8 << 20));
        ushort* Hs = (ushort*)(ws + 58720256);

        gemm_gu_fb<<<dim3(12, 16, NEXP + 1), 256, 0, stream>>>(
            Xb, wg, wu, wsgu, H, Hs, tok, counts);
        down_shared_fb<<<dim3(16, 16), 256, 0, stream>>>(Hs, wsd, out);
        down_routed_fb<<<dim3(16, 4, NEXP), 256, 0, stream>>>(
            H, wd, out, tok, wt, counts);
    }
}

// Round 3
// 866.495 us; speedup vs baseline: 1.1497x; 1.1497x over previous
//
#include <hip/hip_runtime.h>
#include <hip/hip_bf16.h>

// Glm4MoE: B=1,S=2048,D=1024, E=64,K=8,F=768, SF=768, C=512, ROUTED_SCALE=1
//
// R3: f32-direct weights (no conversion pass — weights > L3, streaming f32
// once is the traffic floor). All three GEMMs rebuilt as:
//   - double-buffered LDS, ONE raw s_barrier per K-step, no vmcnt(0) drain:
//     loads for tile k+2 issued in iter k, waited (compiler-counted vmcnt)
//     at the LDS-write in iter k+1.  lgkmcnt(0) before barrier gives ds
//     visibility; sched_barrier(0) pins ordering after it.
//   - per-COLUMN B staging: thread loads 8 strided f32 of one column
//     (wave = 256B coalesced), packs bf16, single ds_write_b128 -> bank
//     pattern at LDSW=40 covers all 32 banks (kills the 8-way write
//     conflict, 2.65e7/dispatch in R0/R1).

typedef unsigned int uint;
typedef unsigned short ushort;
typedef __bf16 v8bf __attribute__((ext_vector_type(8)));
typedef float v4f __attribute__((ext_vector_type(4)));

#define MFMA_BF16 __builtin_amdgcn_mfma_f32_16x16x32_bf16

#define NTOK 2048
#define DMODEL 1024
#define NEXP 64
#define TOPK 8
#define FFN 768
#define CAP 512

// LDS row stride (elements); 80B rows: b128 row-fragment reads are ~2-way
// (free), per-column b128 writes are conflict-free (8-lane bank cycle
// {0,20,8,28,16,4,24,12} x 4-bank span = all 32 banks).
#define LDSW 40

__device__ inline ushort f2bf(float f) {
    uint u = __float_as_uint(f);
    u = (u + 0x7FFFu + ((u >> 16) & 1u)) >> 16;
    return (ushort)u;
}
__device__ inline uint pkbf(float lo, float hi) {
    __hip_bfloat162 h = __float22bfloat162_rn(float2{lo, hi});
    uint u;
    __builtin_memcpy(&u, &h, 4);
    return u;
}

// raw barrier with ds-visibility but NO vmcnt(0) drain
__device__ inline void lds_barrier() {
    asm volatile("s_waitcnt lgkmcnt(0)" ::: "memory");
    __builtin_amdgcn_s_barrier();
    __builtin_amdgcn_sched_barrier(0);
}

// ------------------------------------------------------------- x -> bf16 ----
__global__ __launch_bounds__(256) void x2bf_kernel(
    const float* __restrict__ X, ushort* __restrict__ Xb)
{
    int i = (blockIdx.x * 256 + threadIdx.x) * 4;
    float4 v = *(const float4*)(X + i);
    uint2 o;
    o.x = pkbf(v.x, v.y);
    o.y = pkbf(v.z, v.w);
    *(uint2*)(Xb + i) = o;
}

// ---------------------------------------------------------------- router ----
__global__ __launch_bounds__(64) void router_kernel(
    const float* __restrict__ X, const float* __restrict__ RW,
    int* __restrict__ counts, int* __restrict__ tok_map,
    float* __restrict__ wt_map)
{
    const int t = blockIdx.x;
    const int lane = threadIdx.x;  // == expert id
    const float* xr = X + (size_t)t * DMODEL;
    const float* wr = RW + (size_t)lane * DMODEL;
    float sum = 0.f;
    for (int d = 0; d < DMODEL; d += 4) {
        float4 a = *(const float4*)(wr + d);
        float4 b = *(const float4*)(xr + d);
        sum += a.x * b.x + a.y * b.y + a.z * b.z + a.w * b.w;
    }
    float mx = sum;
    for (int off = 32; off; off >>= 1) mx = fmaxf(mx, __shfl_xor(mx, off));
    float p = __expf(sum - mx);

    float v = p;
    float my_p = 0.f;
    int my_e = 0;
    for (int it = 0; it < TOPK; ++it) {
        float m = v;
        int mi = lane;
        for (int off = 32; off; off >>= 1) {
            float om = __shfl_xor(m, off);
            int oi = __shfl_xor(mi, off);
            if (om > m || (om == m && oi < mi)) { m = om; mi = oi; }
        }
        if (lane == it) { my_p = m; my_e = mi; }
        if (lane == mi) v = -1.f;
    }
    float s = (lane < TOPK) ? my_p : 0.f;
    for (int off = 32; off; off >>= 1) s += __shfl_xor(s, off);
    if (lane < TOPK) {
        float w = my_p / s;
        int slot = atomicAdd(&counts[my_e], 1);
        if (slot < CAP) {
            tok_map[my_e * CAP + slot] = t;
            wt_map[my_e * CAP + slot] = w;
        }
    }
}

// ------------------------------------------------------------- gemm gate/up -
// Block tile 128 x 64, BK=32, 4 waves 2x2 (wave 64x32). z<64: routed expert
// (rows gathered, clamp-dup pad — masked downstream); z==64: shared.
__global__ __launch_bounds__(256) void gemm_gu(
    const ushort* __restrict__ Xb,
    const float* __restrict__ Wg_all, const float* __restrict__ Wu_all,
    const float* __restrict__ Wshared,  // (1024 x 1536): gate 0..767, up 768..1535
    ushort* __restrict__ H, ushort* __restrict__ Hs,
    const int* __restrict__ tok_map, const int* __restrict__ counts)
{
    const int e = blockIdx.z;
    const bool sh = (e == NEXP);
    const int rows = sh ? NTOK : min(counts[e], CAP);
    const int mtile = blockIdx.y, ntile = blockIdx.x;
    if (mtile * 128 >= rows) return;

    const float* Wg;
    const float* Wu;
    int ldw;
    ushort* Hbase;
    if (sh) {
        Wg = Wshared + ntile * 64;
        Wu = Wshared + FFN + ntile * 64;
        ldw = 2 * FFN;
        Hbase = Hs;
    } else {
        Wg = Wg_all + (size_t)e * DMODEL * FFN + ntile * 64;
        Wu = Wu_all + (size_t)e * DMODEL * FFN + ntile * 64;
        ldw = FFN;
        Hbase = H + (size_t)e * CAP * FFN;
    }

    __shared__ ushort As[2][128 * LDSW];
    __shared__ ushort Bg[2][64 * LDSW];
    __shared__ ushort Bu[2][64 * LDSW];

    const int tid = threadIdx.x;
    // A staging: thread -> (row ar, col-half ah), 16B x2 per K-step
    const int ar = tid >> 1, ah = (tid & 1) * 16;
    const int srow = min(mtile * 128 + ar, rows - 1);
    const int trow = sh ? srow : tok_map[e * CAP + srow];
    const ushort* aptr = Xb + (size_t)trow * DMODEL + ah;
    // B staging: thread -> column bn, k-rows [bk, bk+8) of the BK=32 slab
    const int bn = tid & 63;
    const int bk = (tid >> 6) * 8;
    const float* gcol = Wg + (size_t)bk * ldw + bn;
    const float* ucol = Wu + (size_t)bk * ldw + bn;

    const int lane = tid & 63, wv = tid >> 6;
    const int wm = (wv & 1) * 64, wn = (wv >> 1) * 32;
    const int lr = lane & 15, lq = lane >> 4;

    v4f accg[4][2] = {};
    v4f accu[4][2] = {};

    uint4 ra0, ra1;
    float rg[8], ru[8];

    auto GLOAD = [&](int K0) {
        ra0 = *(const uint4*)(aptr + K0);
        ra1 = *(const uint4*)(aptr + K0 + 8);
#pragma unroll
        for (int j = 0; j < 8; ++j) {
            rg[j] = gcol[(size_t)(K0 + j) * ldw];
            ru[j] = ucol[(size_t)(K0 + j) * ldw];
        }
    };
    auto GSTORE = [&](int b) {
        *(uint4*)&As[b][ar * LDSW + ah] = ra0;
        *(uint4*)&As[b][ar * LDSW + ah + 8] = ra1;
        uint4 pg, pu;
        pg.x = pkbf(rg[0], rg[1]); pg.y = pkbf(rg[2], rg[3]);
        pg.z = pkbf(rg[4], rg[5]); pg.w = pkbf(rg[6], rg[7]);
        pu.x = pkbf(ru[0], ru[1]); pu.y = pkbf(ru[2], ru[3]);
        pu.z = pkbf(ru[4], ru[5]); pu.w = pkbf(ru[6], ru[7]);
        *(uint4*)&Bg[b][bn * LDSW + bk] = pg;
        *(uint4*)&Bu[b][bn * LDSW + bk] = pu;
    };
    auto COMPUTE = [&](int b) {
        v8bf a[4], bg[2], bu[2];
#pragma unroll
        for (int mi = 0; mi < 4; ++mi)
            a[mi] = *(const v8bf*)&As[b][(wm + mi * 16 + lr) * LDSW + lq * 8];
#pragma unroll
        for (int ni = 0; ni < 2; ++ni) {
            bg[ni] = *(const v8bf*)&Bg[b][(wn + ni * 16 + lr) * LDSW + lq * 8];
            bu[ni] = *(const v8bf*)&Bu[b][(wn + ni * 16 + lr) * LDSW + lq * 8];
        }
#pragma unroll
        for (int mi = 0; mi < 4; ++mi)
#pragma unroll
            for (int ni = 0; ni < 2; ++ni) {
                accg[mi][ni] = MFMA_BF16(a[mi], bg[ni], accg[mi][ni], 0, 0, 0);
                accu[mi][ni] = MFMA_BF16(a[mi], bu[ni], accu[mi][ni], 0, 0, 0);
            }
    };

    // prologue: LDS[0] <- tile0; regs <- tile1
    GLOAD(0);
    GSTORE(0);
    GLOAD(32);
    lds_barrier();

    for (int k0 = 0, it = 0; k0 < DMODEL; k0 += 32, ++it) {
        const int cur = it & 1;
        if (k0 + 32 < DMODEL) {
            GSTORE(cur ^ 1);                 // stage tile it+1 (counted vmcnt wait)
            if (k0 + 64 < DMODEL) GLOAD(k0 + 64);  // issue tile it+2
            COMPUTE(cur);
            lds_barrier();
        } else {
            COMPUTE(cur);
        }
    }

#pragma unroll
    for (int mi = 0; mi < 4; ++mi)
#pragma unroll
        for (int ni = 0; ni < 2; ++ni)
#pragma unroll
            for (int r = 0; r < 4; ++r) {
                float g = accg[mi][ni][r];
                float u = accu[mi][ni][r];
                float h = (g / (1.f + __expf(-g))) * u;  // silu(g)*u
                int row = mtile * 128 + wm + mi * 16 + lq * 4 + r;
                int col = ntile * 64 + wn + ni * 16 + lr;
                Hbase[(size_t)row * FFN + col] = f2bf(h);
            }
}

// -------------------------------------------------------------- down shared -
__global__ __launch_bounds__(256) void down_shared(
    const ushort* __restrict__ Hs, const float* __restrict__ Wsd,
    float* __restrict__ Out)
{
    const int mtile = blockIdx.y, ntile = blockIdx.x;

    __shared__ ushort As[2][128 * LDSW];
    __shared__ ushort Bt[2][64 * LDSW];

    const int tid = threadIdx.x;
    const int ar = tid >> 1, ah = (tid & 1) * 16;
    const ushort* aptr = Hs + (size_t)(mtile * 128 + ar) * FFN + ah;
    const int bn = tid & 63;
    const int bk = (tid >> 6) * 8;
    const float* wcol = Wsd + (size_t)bk * DMODEL + ntile * 64 + bn;

    const int lane = tid & 63, wv = tid >> 6;
    const int wm = (wv & 1) * 64, wn = (wv >> 1) * 32;
    const int lr = lane & 15, lq = lane >> 4;

    v4f accv[4][2] = {};

    uint4 ra0, ra1;
    float rw[8];

    auto GLOAD = [&](int K0) {
        ra0 = *(const uint4*)(aptr + K0);
        ra1 = *(const uint4*)(aptr + K0 + 8);
#pragma unroll
        for (int j = 0; j < 8; ++j) rw[j] = wcol[(size_t)(K0 + j) * DMODEL];
    };
    auto GSTORE = [&](int b) {
        *(uint4*)&As[b][ar * LDSW + ah] = ra0;
        *(uint4*)&As[b][ar * LDSW + ah + 8] = ra1;
        uint4 pw;
        pw.x = pkbf(rw[0], rw[1]); pw.y = pkbf(rw[2], rw[3]);
        pw.z = pkbf(rw[4], rw[5]); pw.w = pkbf(rw[6], rw[7]);
        *(uint4*)&Bt[b][bn * LDSW + bk] = pw;
    };
    auto COMPUTE = [&](int b) {
        v8bf a[4], bb[2];
#pragma unroll
        for (int mi = 0; mi < 4; ++mi)
            a[mi] = *(const v8bf*)&As[b][(wm + mi * 16 + lr) * LDSW + lq * 8];
#pragma unroll
        for (int ni = 0; ni < 2; ++ni)
            bb[ni] = *(const v8bf*)&Bt[b][(wn + ni * 16 + lr) * LDSW + lq * 8];
#pragma unroll
        for (int mi = 0; mi < 4; ++mi)
#pragma unroll
            for (int ni = 0; ni < 2; ++ni)
                accv[mi][ni] = MFMA_BF16(a[mi], bb[ni], accv[mi][ni], 0, 0, 0);
    };

    GLOAD(0);
    GSTORE(0);
    GLOAD(32);
    lds_barrier();

    for (int k0 = 0, it = 0; k0 < FFN; k0 += 32, ++it) {
        const int cur = it & 1;
        if (k0 + 32 < FFN) {
            GSTORE(cur ^ 1);
            if (k0 + 64 < FFN) GLOAD(k0 + 64);
            COMPUTE(cur);
            lds_barrier();
        } else {
            COMPUTE(cur);
        }
    }

#pragma unroll
    for (int mi = 0; mi < 4; ++mi)
#pragma unroll
        for (int ni = 0; ni < 2; ++ni)
#pragma unroll
            for (int r = 0; r < 4; ++r) {
                int row = mtile * 128 + wm + mi * 16 + lq * 4 + r;
                int col = ntile * 64 + wn + ni * 16 + lr;
                Out[(size_t)row * DMODEL + col] = accv[mi][ni][r];
            }
}

// -------------------------------------------------------------- down routed -
__global__ __launch_bounds__(256) void down_routed(
    const ushort* __restrict__ H, const float* __restrict__ Wd_all,
    float* __restrict__ Out,
    const int* __restrict__ tok_map, const float* __restrict__ wt_map,
    const int* __restrict__ counts)
{
    const int e = blockIdx.z;
    const int rows = min(counts[e], CAP);
    const int mtile = blockIdx.y, ntile = blockIdx.x;
    if (mtile * 128 >= rows) return;

    const ushort* A = H + (size_t)e * CAP * FFN;
    const float* W = Wd_all + (size_t)e * FFN * DMODEL + ntile * 64;

    __shared__ ushort As[2][128 * LDSW];
    __shared__ ushort Bt[2][64 * LDSW];

    const int tid = threadIdx.x;
    const int ar = tid >> 1, ah = (tid & 1) * 16;
    const ushort* aptr = A + (size_t)(mtile * 128 + ar) * FFN + ah;
    const int bn = tid & 63;
    const int bk = (tid >> 6) * 8;
    const float* wcol = W + (size_t)bk * DMODEL + bn;

    const int lane = tid & 63, wv = tid >> 6;
    const int wm = (wv & 1) * 64, wn = (wv >> 1) * 32;
    const int lr = lane & 15, lq = lane >> 4;

    v4f accv[4][2] = {};

    uint4 ra0, ra1;
    float rw[8];

    auto GLOAD = [&](int K0) {
        ra0 = *(const uint4*)(aptr + K0);
        ra1 = *(const uint4*)(aptr + K0 + 8);
#pragma unroll
        for (int j = 0; j < 8; ++j) rw[j] = wcol[(size_t)(K0 + j) * DMODEL];
    };
    auto GSTORE = [&](int b) {
        *(uint4*)&As[b][ar * LDSW + ah] = ra0;
        *(uint4*)&As[b][ar * LDSW + ah + 8] = ra1;
        uint4 pw;
        pw.x = pkbf(rw[0], rw[1]); pw.y = pkbf(rw[2], rw[3]);
        pw.z = pkbf(rw[4], rw[5]); pw.w = pkbf(rw[6], rw[7]);
        *(uint4*)&Bt[b][bn * LDSW + bk] = pw;
    };
    auto COMPUTE = [&](int b) {
        v8bf a[4], bb[2];
#pragma unroll
        for (int mi = 0; mi < 4; ++mi)
            a[mi] = *(const v8bf*)&As[b][(wm + mi * 16 + lr) * LDSW + lq * 8];
#pragma unroll
        for (int ni = 0; ni < 2; ++ni)
            bb[ni] = *(const v8bf*)&Bt[b][(wn + ni * 16 + lr) * LDSW + lq * 8];
#pragma unroll
        for (int mi = 0; mi < 4; ++mi)
#pragma unroll
            for (int ni = 0; ni < 2; ++ni)
                accv[mi][ni] = MFMA_BF16(a[mi], bb[ni], accv[mi][ni], 0, 0, 0);
    };

    GLOAD(0);
    GSTORE(0);
    GLOAD(32);
    lds_barrier();

    for (int k0 = 0, it = 0; k0 < FFN; k0 += 32, ++it) {
        const int cur = it & 1;
        if (k0 + 32 < FFN) {
            GSTORE(cur ^ 1);
            if (k0 + 64 < FFN) GLOAD(k0 + 64);
            COMPUTE(cur);
            lds_barrier();
        } else {
            COMPUTE(cur);
        }
    }

#pragma unroll
    for (int mi = 0; mi < 4; ++mi)
#pragma unroll
        for (int ni = 0; ni < 2; ++ni)
#pragma unroll
            for (int r = 0; r < 4; ++r) {
                int gslot = mtile * 128 + wm + mi * 16 + lq * 4 + r;
                if (gslot < rows) {
                    int t = tok_map[e * CAP + gslot];
                    float w = wt_map[e * CAP + gslot];
                    int col = ntile * 64 + wn + ni * 16 + lr;
                    atomicAdd(&Out[(size_t)t * DMODEL + col], w * accv[mi][ni][r]);
                }
            }
}

// ------------------------------------------------------------------ launch --
extern "C" void kernel_launch(void* const* d_in, const int* in_sizes, int n_in,
                              void* d_out, int out_size, void* d_ws, size_t ws_size,
                              hipStream_t stream)
{
    const float* x    = (const float*)d_in[0];  // (1,2048,1024)
    const float* rw   = (const float*)d_in[1];  // (64,1024)
    const float* wg   = (const float*)d_in[2];  // (64,1024,768)
    const float* wu   = (const float*)d_in[3];  // (64,1024,768)
    const float* wd   = (const float*)d_in[4];  // (64,768,1024)
    const float* wsgu = (const float*)d_in[5];  // (1024,1536)
    const float* wsd  = (const float*)d_in[6];  // (768,1024)
    float* out = (float*)d_out;

    char* ws = (char*)d_ws;
    int*    counts = (int*)(ws + 0);                 // 256 B
    int*    tok    = (int*)(ws + 4096);              // 128 KB
    float*  wt     = (float*)(ws + 139264);          // 128 KB
    ushort* Xb     = (ushort*)(ws + ((size_t)1 << 20));  // 4 MB  [2048][1024] bf16
    ushort* H      = (ushort*)(ws + ((size_t)8 << 20));  // 48 MB [64][512][768] bf16
    ushort* Hs     = (ushort*)(ws + 58720256);           // 3 MB  [2048][768] bf16

    hipMemsetAsync(counts, 0, NEXP * sizeof(int), stream);

    x2bf_kernel<<<NTOK * DMODEL / 1024, 256, 0, stream>>>(x, Xb);
    router_kernel<<<NTOK, 64, 0, stream>>>(x, rw, counts, tok, wt);

    gemm_gu<<<dim3(12, 16, NEXP + 1), 256, 0, stream>>>(Xb, wg, wu, wsgu, H, Hs, tok, counts);

    down_shared<<<dim3(16, 16), 256, 0, stream>>>(Hs, wsd, out);

    down_routed<<<dim3(16, 4, NEXP), 256, 0, stream>>>(H, wd, out, tok, wt, counts);
}